// Round 1
// baseline (2505.154 us; speedup 1.0000x reference)
//
#include <hip/hip_runtime.h>
#include <stdint.h>

constexpr int      BATCH    = 524288;
constexpr int      IN_DIM   = 128;
constexpr int      NREP_    = 2;
constexpr int      ODIM     = 64;          // outputs per rep
constexpr int      ARRAY_SZ = 262144;
constexpr uint64_t PRIME    = 2038074743ull;
constexpr uint32_t RANGE    = ARRAY_SZ - 8 + 1;  // 262137

constexpr int E_TILE = 8;
constexpr int NTILES = BATCH / E_TILE;

__global__ __launch_bounds__(256, 2)
void lma_fused(const float* __restrict__ x,
               const float* __restrict__ hw,
               const float* __restrict__ lsh,
               const void* __restrict__ rnd_raw,
               float* __restrict__ out_idx,   // B*128 floats (idx as f32)
               float* __restrict__ out_val)   // B*64 floats
{
    __shared__ __align__(16) float s_x[E_TILE][IN_DIM];
    __shared__ unsigned long long s_mask[E_TILE][NREP_];

    const int tid  = threadIdx.x;
    const int wave = tid >> 6;
    const int lane = tid & 63;
    const int r    = wave & 1;     // which rep this wave projects
    const int ep   = wave >> 1;    // element-parity group

    // --- hash constants: detect int64 vs int32 layout of random_numbers ---
    uint64_t A, Bc, C0;
    {
        const uint64_t first8 = *reinterpret_cast<const uint64_t*>(rnd_raw);
        if (first8 == PRIME) {   // int64 layout
            const long long* r64 = reinterpret_cast<const long long*>(rnd_raw);
            A  = (uint64_t)r64[1];
            Bc = (uint64_t)r64[2];
            C0 = (uint64_t)r64[3];
        } else {                 // int32 layout
            const int* r32 = reinterpret_cast<const int*>(rnd_raw);
            A  = (uint64_t)(uint32_t)r32[1];
            Bc = (uint64_t)(uint32_t)r32[2];
            C0 = (uint64_t)(uint32_t)r32[3];
        }
    }

    // --- persistent LSH column in registers: col[i] = lsh[i][r*64 + lane] ---
    float col[IN_DIM];
#pragma unroll 8
    for (int i = 0; i < IN_DIM; ++i)
        col[i] = lsh[i * IN_DIM + r * ODIM + lane];

    for (int t = blockIdx.x; t < NTILES; t += gridDim.x) {
        const int base = t * E_TILE;

        __syncthreads();   // previous phase-2 reads of s_mask done; s_x reusable
        // stage 8 elements of x (4 KB) : 256 threads x one float4
        {
            const float4* src = reinterpret_cast<const float4*>(x + (size_t)base * IN_DIM);
            reinterpret_cast<float4*>(&s_x[0][0])[tid] = src[tid];
        }
        __syncthreads();

        // -------- phase 1: projections, 4 (element, r) pairs per wave --------
#pragma unroll
        for (int g = 0; g < 2; ++g) {
            const int eA = ep + g * 4;        // {0,2,4,6} or {1,3,5,7}
            const int eB = ep + g * 4 + 2;
            const float* xA = s_x[eA];
            const float* xB = s_x[eB];
            float accA = 0.0f, accB = 0.0f;
            // strictly sequential accumulation over i (matches reference order);
            // ILP across the two independent elements.
#pragma unroll
            for (int i = 0; i < IN_DIM; i += 4) {
                const float4 va = *reinterpret_cast<const float4*>(xA + i);
                const float4 vb = *reinterpret_cast<const float4*>(xB + i);
                accA = __builtin_fmaf(va.x, col[i + 0], accA);
                accB = __builtin_fmaf(vb.x, col[i + 0], accB);
                accA = __builtin_fmaf(va.y, col[i + 1], accA);
                accB = __builtin_fmaf(vb.y, col[i + 1], accB);
                accA = __builtin_fmaf(va.z, col[i + 2], accA);
                accB = __builtin_fmaf(vb.z, col[i + 2], accB);
                accA = __builtin_fmaf(va.w, col[i + 3], accA);
                accB = __builtin_fmaf(vb.w, col[i + 3], accB);
            }
            const unsigned long long mA = __ballot(accA > 0.0f);
            const unsigned long long mB = __ballot(accB > 0.0f);
            if (lane == 0) {
                s_mask[eA][r] = mA;
                s_mask[eB][r] = mB;
            }
        }
        __syncthreads();

        // -------- phase 2: hash + gather + store, 2 elements per wave --------
#pragma unroll
        for (int q = 0; q < 2; ++q) {
            const int e = wave * 2 + q;
            const unsigned long long m0 = s_mask[e][0];
            const unsigned long long m1 = s_mask[e][1];
            const int c = lane >> 3;          // chunk id 0..7
            const int s = lane & 7;           // slot within chunk
            const uint32_t srp0 = (uint32_t)(m0 >> (c * 8)) & 0xffu;
            const uint32_t srp1 = (uint32_t)(m1 >> (c * 8)) & 0xffu;
            const uint64_t h0 = (A * srp0 + Bc * (uint64_t)c + C0) % PRIME;
            const uint64_t h1 = (A * srp1 + Bc * (uint64_t)c + C0) % PRIME;
            const uint32_t loc0 = (uint32_t)h0 % RANGE;
            const uint32_t loc1 = (uint32_t)h1 % RANGE;
            const uint32_t i0 = loc0 + (uint32_t)s;                 // rep 0
            const uint32_t i1 = (uint32_t)ARRAY_SZ + loc1 + (uint32_t)s; // rep 1
            const float w0 = hw[i0];
            const float w1 = hw[i1];
            const size_t b = (size_t)(base + e);
            out_idx[b * 128 + lane]      = (float)i0;
            out_idx[b * 128 + 64 + lane] = (float)i1;
            out_val[b * 64 + lane]       = (w0 + w1) * 0.5f;
        }
    }
}

extern "C" void kernel_launch(void* const* d_in, const int* in_sizes, int n_in,
                              void* d_out, int out_size, void* d_ws, size_t ws_size,
                              hipStream_t stream) {
    const float* x   = (const float*)d_in[0];
    const float* hw  = (const float*)d_in[1];
    const float* lsh = (const float*)d_in[2];
    const void*  rnd = (const void*)d_in[3];

    float* out_idx = (float*)d_out;
    float* out_val = out_idx + (size_t)BATCH * (NREP_ * ODIM);

    const int grid = 4096;
    lma_fused<<<grid, 256, 0, stream>>>(x, hw, lsh, rnd, out_idx, out_val);
}

// Round 2
// 1569.707 us; speedup vs baseline: 1.5959x; 1.5959x over previous
//
#include <hip/hip_runtime.h>
#include <stdint.h>

constexpr int      BATCH    = 524288;
constexpr int      IN_DIM   = 128;
constexpr int      NREP_    = 2;
constexpr int      ODIM     = 64;          // outputs per rep
constexpr int      ARRAY_SZ = 262144;
constexpr uint64_t PRIME    = 2038074743ull;
constexpr uint32_t RANGE    = ARRAY_SZ - 8 + 1;  // 262137

constexpr int E_TILE = 8;
constexpr int NTILES = BATCH / E_TILE;

__global__ __launch_bounds__(256, 2)
void lma_fused(const float* __restrict__ x,
               const float* __restrict__ hw,
               const float* __restrict__ lsh,
               const void* __restrict__ rnd_raw,
               float* __restrict__ out_idx,   // B*128 floats (idx as f32)
               float* __restrict__ out_val)   // B*64 floats
{
    __shared__ __align__(16) float s_x[E_TILE][IN_DIM];
    __shared__ unsigned long long s_mask[E_TILE][NREP_];

    const int tid  = threadIdx.x;
    const int wave = tid >> 6;
    const int lane = tid & 63;
    const int r    = wave & 1;     // which rep this wave projects
    const int ep   = wave >> 1;    // element-parity group

    // --- hash constants: detect int64 vs int32 layout of random_numbers ---
    uint64_t A, Bc, C0;
    {
        const uint64_t first8 = *reinterpret_cast<const uint64_t*>(rnd_raw);
        if (first8 == PRIME) {   // int64 layout
            const long long* r64 = reinterpret_cast<const long long*>(rnd_raw);
            A  = (uint64_t)r64[1];
            Bc = (uint64_t)r64[2];
            C0 = (uint64_t)r64[3];
        } else {                 // int32 layout
            const int* r32 = reinterpret_cast<const int*>(rnd_raw);
            A  = (uint64_t)(uint32_t)r32[1];
            Bc = (uint64_t)(uint32_t)r32[2];
            C0 = (uint64_t)(uint32_t)r32[3];
        }
    }

    // --- persistent LSH column in registers: col[i] = lsh[i][r*64 + lane] ---
    // FULL unroll: every index compile-time constant so col[] lives in VGPRs
    // (partial unroll => runtime index => scratch => 9 GB of spill traffic).
    float col[IN_DIM];
#pragma unroll
    for (int i = 0; i < IN_DIM; ++i)
        col[i] = lsh[i * IN_DIM + r * ODIM + lane];

    for (int t = blockIdx.x; t < NTILES; t += gridDim.x) {
        const int base = t * E_TILE;

        __syncthreads();   // previous phase-2 reads of s_mask done; s_x reusable
        // stage 8 elements of x (4 KB) : 256 threads x one float4
        {
            const float4* src = reinterpret_cast<const float4*>(x + (size_t)base * IN_DIM);
            reinterpret_cast<float4*>(&s_x[0][0])[tid] = src[tid];
        }
        __syncthreads();

        // -------- phase 1: projections, 4 (element, r) pairs per wave --------
#pragma unroll
        for (int g = 0; g < 2; ++g) {
            const int eA = ep + g * 4;        // {0,2,4,6} or {1,3,5,7}
            const int eB = ep + g * 4 + 2;
            const float* xA = s_x[eA];
            const float* xB = s_x[eB];
            float accA = 0.0f, accB = 0.0f;
            // strictly sequential accumulation over i (matches reference order);
            // ILP across the two independent elements.
#pragma unroll
            for (int i = 0; i < IN_DIM; i += 4) {
                const float4 va = *reinterpret_cast<const float4*>(xA + i);
                const float4 vb = *reinterpret_cast<const float4*>(xB + i);
                accA = __builtin_fmaf(va.x, col[i + 0], accA);
                accB = __builtin_fmaf(vb.x, col[i + 0], accB);
                accA = __builtin_fmaf(va.y, col[i + 1], accA);
                accB = __builtin_fmaf(vb.y, col[i + 1], accB);
                accA = __builtin_fmaf(va.z, col[i + 2], accA);
                accB = __builtin_fmaf(vb.z, col[i + 2], accB);
                accA = __builtin_fmaf(va.w, col[i + 3], accA);
                accB = __builtin_fmaf(vb.w, col[i + 3], accB);
            }
            const unsigned long long mA = __ballot(accA > 0.0f);
            const unsigned long long mB = __ballot(accB > 0.0f);
            if (lane == 0) {
                s_mask[eA][r] = mA;
                s_mask[eB][r] = mB;
            }
        }
        __syncthreads();

        // -------- phase 2: hash + gather + store, 2 elements per wave --------
#pragma unroll
        for (int q = 0; q < 2; ++q) {
            const int e = wave * 2 + q;
            const unsigned long long m0 = s_mask[e][0];
            const unsigned long long m1 = s_mask[e][1];
            const int c = lane >> 3;          // chunk id 0..7
            const int s = lane & 7;           // slot within chunk
            const uint32_t srp0 = (uint32_t)(m0 >> (c * 8)) & 0xffu;
            const uint32_t srp1 = (uint32_t)(m1 >> (c * 8)) & 0xffu;
            const uint64_t h0 = (A * srp0 + Bc * (uint64_t)c + C0) % PRIME;
            const uint64_t h1 = (A * srp1 + Bc * (uint64_t)c + C0) % PRIME;
            const uint32_t loc0 = (uint32_t)h0 % RANGE;
            const uint32_t loc1 = (uint32_t)h1 % RANGE;
            const uint32_t i0 = loc0 + (uint32_t)s;                 // rep 0
            const uint32_t i1 = (uint32_t)ARRAY_SZ + loc1 + (uint32_t)s; // rep 1
            const float w0 = hw[i0];
            const float w1 = hw[i1];
            const size_t b = (size_t)(base + e);
            out_idx[b * 128 + lane]      = (float)i0;
            out_idx[b * 128 + 64 + lane] = (float)i1;
            out_val[b * 64 + lane]       = (w0 + w1) * 0.5f;
        }
    }
}

extern "C" void kernel_launch(void* const* d_in, const int* in_sizes, int n_in,
                              void* d_out, int out_size, void* d_ws, size_t ws_size,
                              hipStream_t stream) {
    const float* x   = (const float*)d_in[0];
    const float* hw  = (const float*)d_in[1];
    const float* lsh = (const float*)d_in[2];
    const void*  rnd = (const void*)d_in[3];

    float* out_idx = (float*)d_out;
    float* out_val = out_idx + (size_t)BATCH * (NREP_ * ODIM);

    const int grid = 4096;
    lma_fused<<<grid, 256, 0, stream>>>(x, hw, lsh, rnd, out_idx, out_val);
}